// Round 10
// baseline (142.468 us; speedup 1.0000x reference)
//
#include <hip/hip_runtime.h>

// GNN: 3x GraphConv(64->64) + ReLU, mean-pool over sorted batch, 2 dense layers.
// R1: scatter-atomics -> device-built CSR + gather (no float atomics).
// R2: single-block scan -> 3-phase multi-block scan.
// R3: GEMM -> bf16 MFMA (f32 acc); 16-bit messages/indices.
// R4: pool parallelized.
// R5: CSR build -> 2-pass radix partition (bucket = dst>>8).
// R6: agg-first restructure; all inter-layer state bf16.  [142us]
// R7: gather+gemm fusion REGRESSED (164us) -> reverted.
// R8: prep-baked pre-swizzled W images; gather 2-deep ILP.  [124.5us]
// R9: mean-pool fused into gemm3 epilogue (LDS ds_add_f32 partials ->
//     ~150 global f32 atomics/block; no dense layer-3 output); pool_mlp
//     replaced by tiny mlp_head reading the 128KB pooled buffer.

#define NFEAT 64
#define BCAP  6144    // pairs capacity per bucket (mean 4096, +32 sigma)

typedef unsigned short u16;
typedef unsigned int   u32;
typedef __attribute__((ext_vector_type(8))) short short8;
typedef __attribute__((ext_vector_type(4))) float f32x4;

// f32 -> bf16 round-to-nearest-even
__device__ __forceinline__ u16 f2bf(float f) {
    u32 u = __float_as_uint(f);
    u32 r = (u + 0x7fffu + ((u >> 16) & 1u)) >> 16;
    return (u16)r;
}
__device__ __forceinline__ float bflo(u32 u) { return __uint_as_float(u << 16); }
__device__ __forceinline__ float bfhi(u32 u) { return __uint_as_float(u & 0xffff0000u); }

// ---------------------------------------------------------------------------
// prep: cast x f32->bf16; bake W images (transpose+bf16+XOR swizzle, exactly
// the gemm LDS layout); zero bcnt; zero pooled.
// ---------------------------------------------------------------------------
#define CAST_BLKS 1600
__global__ __launch_bounds__(256) void prep(
    const float* __restrict__ x, u16* __restrict__ xb, int n8,
    const float* __restrict__ W1r, const float* __restrict__ W1l,
    const float* __restrict__ W2r, const float* __restrict__ W2l,
    const float* __restrict__ W3r, const float* __restrict__ W3l,
    u16* __restrict__ wimg, int* __restrict__ bcnt, int nbuck,
    float* __restrict__ pooled, int ng)
{
    const int bid = blockIdx.x;
    const int tid = threadIdx.x;

    if (bid < CAST_BLKS) {
        int i = bid * 256 + tid;
        if (i < n8) {
            const float4* p = (const float4*)(x + (size_t)i * 8);
            float4 a = p[0], b = p[1];
            uint4 o;
            o.x = f2bf(a.x) | ((u32)f2bf(a.y) << 16);
            o.y = f2bf(a.z) | ((u32)f2bf(a.w) << 16);
            o.z = f2bf(b.x) | ((u32)f2bf(b.y) << 16);
            o.w = f2bf(b.z) | ((u32)f2bf(b.w) << 16);
            *(uint4*)(xb + (size_t)i * 8) = o;
        }
    } else if (bid < CAST_BLKS + 6) {
        int m = bid - CAST_BLKS;            // 0..5
        int layer = m >> 1;                 // 0..2
        int isrel = m & 1;                  // 0 root, 1 rel
        const float* W = (m == 0) ? W1r : (m == 1) ? W1l :
                         (m == 2) ? W2r : (m == 3) ? W2l :
                         (m == 4) ? W3r : W3l;
        u16* img = wimg + (size_t)layer * (64 * 128);
        #pragma unroll
        for (int it = 0; it < 16; ++it) {
            int flat = it * 256 + tid;      // 0..4095
            int k = flat >> 6, n = flat & 63;
            int ck = (k >> 3) + (isrel ? 8 : 0);
            int kin = k & 7;
            img[n * 128 + (((ck ^ (n & 7)) << 3) | kin)] = f2bf(W[k * 64 + n]);
        }
    } else if (bid == CAST_BLKS + 6) {
        if (tid < nbuck) bcnt[tid] = 0;
    } else {
        int i = (bid - (CAST_BLKS + 7)) * 256 + tid;   // float4 index
        if (i < ng * 16) ((float4*)pooled)[i] = make_float4(0.f, 0.f, 0.f, 0.f);
    }
}

// ---------------------------------------------------------------------------
// GEMM (MFMA, K=128): t = [hin | agg] @ [Wroot; Wrel] + b
//   fuse_pool == 0: hout = bf16(relu(t))
//   fuse_pool == 1: pooled[batch[row]] += relu(t) (LDS partials -> global
//                   atomics); no dense output.
// W staged from pre-swizzled image (pure uint4 copy).
// ---------------------------------------------------------------------------
__global__ __launch_bounds__(256) void gemm_cat(
    const u16* __restrict__ hin, const u16* __restrict__ agg,
    const u16* __restrict__ wimg, const float* __restrict__ bias,
    u16* __restrict__ hout, int n_rows,
    int fuse_pool, const int* __restrict__ batch, float* __restrict__ pooled)
{
    __shared__ u16 als[64 * 128];   // [row][k0..127], swizzled; reused as pacc
    __shared__ u16 wls[64 * 128];   // [col][k0..127], swizzled (from image)

    const int tid = threadIdx.x;
    const int row0 = blockIdx.x * 64;

    // stage W: linear 16KB copy
    {
        const uint4* wsrc = (const uint4*)wimg;
        uint4* wdst = (uint4*)wls;
        #pragma unroll
        for (int it = 0; it < 4; ++it)
            wdst[it * 256 + tid] = wsrc[it * 256 + tid];
    }

    // stage A: 1024 16B chunks; chunk ch<8 from hin, else agg
    #pragma unroll
    for (int it = 0; it < 4; ++it) {
        int id = it * 256 + tid;
        int r = id >> 4, ch = id & 15;
        int gr = row0 + r;
        uint4 v = make_uint4(0, 0, 0, 0);
        if (gr < n_rows) {
            const u16* sp = (ch < 8) ? (hin + (size_t)gr * 64 + ch * 8)
                                     : (agg + (size_t)gr * 64 + (ch - 8) * 8);
            v = *(const uint4*)sp;
        }
        *(uint4*)&als[r * 128 + ((ch ^ (r & 7)) << 3)] = v;
    }
    __syncthreads();

    const int w = tid >> 6, l = tid & 63;
    const int l15 = l & 15;
    const int wrow0 = w * 16;

    short8 afr[4];
    #pragma unroll
    for (int ks = 0; ks < 4; ++ks) {
        int r = wrow0 + l15;
        int ck = ks * 4 + (l >> 4);
        afr[ks] = *(const short8*)&als[r * 128 + ((ck ^ (r & 7)) << 3)];
    }
    short8 bfr[4][4];
    #pragma unroll
    for (int nl = 0; nl < 4; ++nl)
        #pragma unroll
        for (int ks = 0; ks < 4; ++ks) {
            int cl = nl * 16 + l15;
            int ck = ks * 4 + (l >> 4);
            bfr[nl][ks] = *(const short8*)&wls[cl * 128 + ((ck ^ (cl & 7)) << 3)];
        }

    f32x4 acc[4];
    #pragma unroll
    for (int nl = 0; nl < 4; ++nl) {
        float bv = bias[nl * 16 + l15];
        f32x4 iv = {bv, bv, bv, bv};
        acc[nl] = iv;
    }
    #pragma unroll
    for (int nl = 0; nl < 4; ++nl)
        #pragma unroll
        for (int ks = 0; ks < 4; ++ks)
            acc[nl] = __builtin_amdgcn_mfma_f32_16x16x32_bf16(
                afr[ks], bfr[nl][ks], acc[nl], 0, 0, 0);

    // C/D: col = l&15, row = (l>>4)*4 + reg
    const int rg = (l >> 4) * 4;

    if (!fuse_pool) {
        #pragma unroll
        for (int reg = 0; reg < 4; ++reg) {
            int row = row0 + wrow0 + rg + reg;
            if (row < n_rows) {
                #pragma unroll
                for (int nl = 0; nl < 4; ++nl)
                    hout[(size_t)row * 64 + nl * 16 + l15] =
                        f2bf(fmaxf(acc[nl][reg], 0.f));
            }
        }
    } else {
        // ---- fused mean-pool accumulation ----
        // als is dead (all ds_reads drained at the barrier) -> overlay pacc.
        float* pacc = (float*)als;       // [64][64] f32 = 16KB
        __syncthreads();
        #pragma unroll
        for (int it = 0; it < 4; ++it)
            ((float4*)pacc)[it * 256 + tid] = make_float4(0.f, 0.f, 0.f, 0.f);
        __syncthreads();

        const int glo = batch[row0];
        #pragma unroll
        for (int reg = 0; reg < 4; ++reg) {
            int row = row0 + wrow0 + rg + reg;
            if (row < n_rows) {
                int gi = batch[row] - glo;
                #pragma unroll
                for (int nl = 0; nl < 4; ++nl) {
                    float v = fmaxf(acc[nl][reg], 0.f);
                    int col = nl * 16 + l15;
                    if (gi < 64) atomicAdd(&pacc[gi * 64 + col], v);
                    else         unsafeAtomicAdd(&pooled[(size_t)(glo + gi) * 64 + col], v);
                }
            }
        }
        __syncthreads();

        int last = row0 + 63; if (last > n_rows - 1) last = n_rows - 1;
        int span = batch[last] - glo + 1;
        if (span > 64) span = 64;
        for (int i = tid; i < span * 64; i += 256) {
            float v = pacc[i];
            if (v != 0.f) {
                int gi = i >> 6, col = i & 63;
                unsafeAtomicAdd(&pooled[(size_t)(glo + gi) * 64 + col], v);
            }
        }
    }
}

// ---------------------------------------------------------------------------
// CSR build (R5): partition by dst bucket, then per-bucket local build.
// ---------------------------------------------------------------------------
__global__ __launch_bounds__(256) void part_bucket(
    const int* __restrict__ src, const int* __restrict__ dst, int ne,
    int* __restrict__ bcnt, u32* __restrict__ pairs)
{
    __shared__ int lcnt[256];
    __shared__ int lbase[256];
    const int t = threadIdx.x;
    const int e0 = blockIdx.x * 4096;

    lcnt[t] = 0;
    __syncthreads();

    int s_[16], d_[16];
    #pragma unroll
    for (int i = 0; i < 16; ++i) {
        int e = e0 + i * 256 + t;
        if (e < ne) { s_[i] = src[e]; d_[i] = dst[e]; }
        else        { s_[i] = 0;      d_[i] = -1; }
    }
    #pragma unroll
    for (int i = 0; i < 16; ++i)
        if (d_[i] >= 0) atomicAdd(&lcnt[d_[i] >> 8], 1);
    __syncthreads();

    {
        int c = lcnt[t];
        lbase[t] = (c > 0) ? atomicAdd(&bcnt[t], c) : 0;
    }
    __syncthreads();
    lcnt[t] = 0;
    __syncthreads();

    #pragma unroll
    for (int i = 0; i < 16; ++i)
        if (d_[i] >= 0) {
            int b = d_[i] >> 8;
            int o = atomicAdd(&lcnt[b], 1);
            pairs[(size_t)b * BCAP + lbase[b] + o] =
                (u32)s_[i] | ((u32)(d_[i] & 255) << 16);
        }
}

__global__ __launch_bounds__(64) void scan_offsets(const int* __restrict__ bcnt, int nbuck,
                                                   int* __restrict__ boff,
                                                   int* __restrict__ row_ptr, int nn) {
    const int t = threadIdx.x;
    int carry = 0;
    for (int base = 0; base < nbuck; base += 64) {
        int i = base + t;
        int v = (i < nbuck) ? bcnt[i] : 0;
        int inc = v;
        #pragma unroll
        for (int off = 1; off < 64; off <<= 1) {
            int x = __shfl_up(inc, off);
            if (t >= off) inc += x;
        }
        if (i < nbuck) boff[i] = carry + inc - v;
        carry += __shfl(inc, 63);
    }
    if (t == 0) row_ptr[nn] = carry;
}

__global__ __launch_bounds__(256) void build_csr(
    const u32* __restrict__ pairs, const int* __restrict__ bcnt,
    const int* __restrict__ boff, int nn,
    int* __restrict__ row_ptr, u16* __restrict__ csr_src)
{
    __shared__ u32 lp[BCAP];
    __shared__ int deg[256];
    __shared__ int tsum[256];
    __shared__ int lofs[256];
    __shared__ int cur[256];

    const int b = blockIdx.x;
    const int t = threadIdx.x;
    const int cnt   = bcnt[b];
    const int ebase = boff[b];
    const int n0    = b * 256;

    deg[t] = 0; cur[t] = 0;
    __syncthreads();

    for (int i = t; i < cnt; i += 256) {
        u32 p = pairs[(size_t)b * BCAP + i];
        lp[i] = p;
        atomicAdd(&deg[p >> 16], 1);
    }
    __syncthreads();

    tsum[t] = deg[t];
    __syncthreads();
    #pragma unroll
    for (int off = 1; off < 256; off <<= 1) {
        int x = (t >= off) ? tsum[t - off] : 0;
        __syncthreads();
        tsum[t] += x;
        __syncthreads();
    }
    int excl = (t > 0 ? tsum[t - 1] : 0);
    lofs[t] = ebase + excl;
    int node = n0 + t;
    if (node < nn) row_ptr[node] = ebase + excl;
    __syncthreads();

    for (int i = t; i < cnt; i += 256) {
        u32 p = lp[i];
        int dl = p >> 16;
        int pos = lofs[dl] + atomicAdd(&cur[dl], 1);
        csr_src[pos] = (u16)(p & 0xffffu);
    }
}

// ---------------------------------------------------------------------------
// Gather-aggregate (R6 + 2-deep ILP): agg[node] = bf16(sum h_bf[src_j])
// ---------------------------------------------------------------------------
__global__ __launch_bounds__(256) void gather_agg(
    const u16* __restrict__ hb,
    const int* __restrict__ row_ptr,
    const u16* __restrict__ csr_src,
    u16* __restrict__ agg,
    int nn)
{
    const int node = blockIdx.x * 4 + (threadIdx.x >> 6);
    const int l = threadIdx.x & 63;
    if (node >= nn) return;
    const int s = row_ptr[node];
    const int e = row_ptr[node + 1];
    const int es = l >> 3;      // edge slot 0..7
    const int c  = l & 7;       // 16B chunk 0..7
    const uint4* hv = (const uint4*)hb;   // row = 8 uint4

    float a0=0.f,a1=0.f,a2=0.f,a3=0.f,a4=0.f,a5=0.f,a6=0.f,a7=0.f;
    for (int j = s; j < e; j += 16) {
        int je0 = j + es, je1 = j + es + 8;
        int jj0 = (je0 < e) ? je0 : (e - 1);
        int jj1 = (je1 < e) ? je1 : (e - 1);
        float m0 = (je0 < e) ? 1.f : 0.f;
        float m1 = (je1 < e) ? 1.f : 0.f;
        int s0 = csr_src[jj0];
        int s1 = csr_src[jj1];
        uint4 q0 = hv[(size_t)s0 * 8 + c];
        uint4 q1 = hv[(size_t)s1 * 8 + c];
        a0 = fmaf(m0, bflo(q0.x), a0);  a1 = fmaf(m0, bfhi(q0.x), a1);
        a2 = fmaf(m0, bflo(q0.y), a2);  a3 = fmaf(m0, bfhi(q0.y), a3);
        a4 = fmaf(m0, bflo(q0.z), a4);  a5 = fmaf(m0, bfhi(q0.z), a5);
        a6 = fmaf(m0, bflo(q0.w), a6);  a7 = fmaf(m0, bfhi(q0.w), a7);
        a0 = fmaf(m1, bflo(q1.x), a0);  a1 = fmaf(m1, bfhi(q1.x), a1);
        a2 = fmaf(m1, bflo(q1.y), a2);  a3 = fmaf(m1, bfhi(q1.y), a3);
        a4 = fmaf(m1, bflo(q1.z), a4);  a5 = fmaf(m1, bfhi(q1.z), a5);
        a6 = fmaf(m1, bflo(q1.w), a6);  a7 = fmaf(m1, bfhi(q1.w), a7);
    }
    #pragma unroll
    for (int msk = 8; msk <= 32; msk <<= 1) {
        a0 += __shfl_xor(a0, msk); a1 += __shfl_xor(a1, msk);
        a2 += __shfl_xor(a2, msk); a3 += __shfl_xor(a3, msk);
        a4 += __shfl_xor(a4, msk); a5 += __shfl_xor(a5, msk);
        a6 += __shfl_xor(a6, msk); a7 += __shfl_xor(a7, msk);
    }
    if (es == 0) {
        uint4 o;
        o.x = f2bf(a0) | ((u32)f2bf(a1) << 16);
        o.y = f2bf(a2) | ((u32)f2bf(a3) << 16);
        o.z = f2bf(a4) | ((u32)f2bf(a5) << 16);
        o.w = f2bf(a6) | ((u32)f2bf(a7) << 16);
        ((uint4*)agg)[(size_t)node * 8 + c] = o;
    }
}

// ---------------------------------------------------------------------------
// MLP head: one 64-thread block per graph; mean from pooled sums + counts
// (binary search on sorted batch), then 64->64->2 MLP.
// ---------------------------------------------------------------------------
__global__ __launch_bounds__(64) void mlp_head(
    const float* __restrict__ pooled,
    const int* __restrict__ batch, int n_nodes,
    const float* __restrict__ Wf1, const float* __restrict__ bf1,
    const float* __restrict__ Wf2, const float* __restrict__ bf2,
    float* __restrict__ out, int n_graphs)
{
    const int g = blockIdx.x;
    const int lane = threadIdx.x;

    int lo = 0, hi = n_nodes;
    while (lo < hi) { int mid = (lo + hi) >> 1; if (batch[mid] < g) lo = mid + 1; else hi = mid; }
    int s = lo;
    lo = s; hi = n_nodes;
    while (lo < hi) { int mid = (lo + hi) >> 1; if (batch[mid] < g + 1) lo = mid + 1; else hi = mid; }
    int e = lo;

    float inv = 1.0f / (float)((e - s) > 0 ? (e - s) : 1);

    __shared__ float pl[64];
    __shared__ float md[64];
    pl[lane] = pooled[(size_t)g * 64 + lane] * inv;
    __syncthreads();

    float m = bf1[lane];
    #pragma unroll 8
    for (int k = 0; k < 64; ++k)
        m += pl[k] * Wf1[k * 64 + lane];
    md[lane] = m;
    __syncthreads();

    if (lane < 2) {
        float o = bf2[lane];
        #pragma unroll 8
        for (int k = 0; k < 64; ++k)
            o += md[k] * Wf2[k * 2 + lane];
        out[(size_t)g * 2 + lane] = o;
    }
}

// ---------------------------------------------------------------------------
extern "C" void kernel_launch(void* const* d_in, const int* in_sizes, int n_in,
                              void* d_out, int out_size, void* d_ws, size_t ws_size,
                              hipStream_t stream) {
    const float* x     = (const float*)d_in[0];
    const int*   ei    = (const int*)d_in[1];
    const int*   batch = (const int*)d_in[2];
    const float* W1_rel  = (const float*)d_in[3];
    const float* W1_root = (const float*)d_in[4];
    const float* b1      = (const float*)d_in[5];
    const float* W2_rel  = (const float*)d_in[6];
    const float* W2_root = (const float*)d_in[7];
    const float* b2      = (const float*)d_in[8];
    const float* W3_rel  = (const float*)d_in[9];
    const float* W3_root = (const float*)d_in[10];
    const float* b3      = (const float*)d_in[11];
    const float* Wf1     = (const float*)d_in[12];
    const float* bf1     = (const float*)d_in[13];
    const float* Wf2     = (const float*)d_in[14];
    const float* bf2     = (const float*)d_in[15];

    const int NN = in_sizes[0] / NFEAT;      // 50000
    const int NE = in_sizes[1] / 2;          // 800000
    const int NG = out_size / 2;             // 500

    const int* src = ei;
    const int* dst = ei + NE;

    const int nbuck = (NN + 255) / 256;      // 196

    u16*   hA      = (u16*)d_ws;                             // NN*64 bf16
    u16*   hB      = hA + (size_t)NN * NFEAT;                // NN*64 bf16 (also x_bf)
    u16*   aggb    = hB + (size_t)NN * NFEAT;                // NN*64 bf16
    int*   row_ptr = (int*)(aggb + (size_t)NN * NFEAT);      // NN+1
    int*   bcnt    = row_ptr + (NN + 1);                     // nbuck
    int*   boff    = bcnt + nbuck;                           // nbuck
    u32*   pairs   = (u32*)(boff + nbuck);                   // nbuck*BCAP
    u16*   csr_src = (u16*)(pairs + (size_t)nbuck * BCAP);   // NE u16
    u16*   wimg    = csr_src + NE;                           // 3*64*128 u16
    float* pooled  = (float*)(wimg + 3 * 64 * 128);          // NG*64 f32

    const int gemm_grid = (NN + 63) / 64;
    const int node_grid = (NN + 3) / 4;
    const int part_grid = (NE + 4095) / 4096;                // 196
    const int n8        = NN * NFEAT / 8;                    // 400000
    const int pz_blocks = (NG * 16 + 255) / 256;             // pooled zero (float4)

    // ---- prep: x->bf16 (hB), W images, zero bcnt, zero pooled ----
    prep<<<CAST_BLKS + 7 + pz_blocks, 256, 0, stream>>>(x, hB, n8,
        W1_root, W1_rel, W2_root, W2_rel, W3_root, W3_rel,
        wimg, bcnt, nbuck, pooled, NG);

    // ---- CSR build (reused by all 3 layers) ----
    part_bucket<<<part_grid, 256, 0, stream>>>(src, dst, NE, bcnt, pairs);
    scan_offsets<<<1, 64, 0, stream>>>(bcnt, nbuck, boff, row_ptr, NN);
    build_csr<<<nbuck, 256, 0, stream>>>(pairs, bcnt, boff, NN, row_ptr, csr_src);

    // Layer 1: x_bf (=hB) -> hA
    gather_agg<<<node_grid, 256, 0, stream>>>(hB, row_ptr, csr_src, aggb, NN);
    gemm_cat<<<gemm_grid, 256, 0, stream>>>(hB, aggb, wimg, b1, hA, NN,
                                            0, batch, pooled);
    // Layer 2: hA -> hB
    gather_agg<<<node_grid, 256, 0, stream>>>(hA, row_ptr, csr_src, aggb, NN);
    gemm_cat<<<gemm_grid, 256, 0, stream>>>(hA, aggb, wimg + 64 * 128, b2, hB, NN,
                                            0, batch, pooled);
    // Layer 3: hB -> pooled (fused mean-pool accumulation; no dense output)
    gather_agg<<<node_grid, 256, 0, stream>>>(hB, row_ptr, csr_src, aggb, NN);
    gemm_cat<<<gemm_grid, 256, 0, stream>>>(hB, aggb, wimg + 2 * 64 * 128, b3, hA, NN,
                                            1, batch, pooled);

    // MLP head over pooled sums
    mlp_head<<<NG, 64, 0, stream>>>(pooled, batch, NN, Wf1, bf1, Wf2, bf2,
                                    (float*)d_out, NG);
}

// Round 11
// 121.709 us; speedup vs baseline: 1.1706x; 1.1706x over previous
//
#include <hip/hip_runtime.h>

// GNN: 3x GraphConv(64->64) + ReLU, mean-pool over sorted batch, 2 dense layers.
// R1: scatter-atomics -> device-built CSR + gather (no float atomics).
// R2: single-block scan -> 3-phase multi-block scan.
// R3: GEMM -> bf16 MFMA (f32 acc); 16-bit messages/indices.
// R4: pool parallelized.
// R5: CSR build -> 2-pass radix partition (bucket = dst>>8).
// R6: agg-first restructure; all inter-layer state bf16.  [142us]
// R7: gather+gemm fusion REGRESSED (164us) -> reverted.
// R8: prep-baked pre-swizzled W images; gather 2-deep ILP.  [124.5us]
// R9: pool fused into gemm3 epilogue REGRESSED (142.5us: same-address LDS
//     atomics serialize -- 64-row block spans ~1 graph) -> reverted.
// R10: R8 + scan_offsets folded into build_csr (each bucket block computes
//      its own prefix over bcnt; 11 -> 10 launches, removes the 1-block
//      serialization point).

#define NFEAT 64
#define BCAP  6144    // pairs capacity per bucket (mean 4096, +32 sigma)

typedef unsigned short u16;
typedef unsigned int   u32;
typedef __attribute__((ext_vector_type(8))) short short8;
typedef __attribute__((ext_vector_type(4))) float f32x4;

// f32 -> bf16 round-to-nearest-even
__device__ __forceinline__ u16 f2bf(float f) {
    u32 u = __float_as_uint(f);
    u32 r = (u + 0x7fffu + ((u >> 16) & 1u)) >> 16;
    return (u16)r;
}
__device__ __forceinline__ float bflo(u32 u) { return __uint_as_float(u << 16); }
__device__ __forceinline__ float bfhi(u32 u) { return __uint_as_float(u & 0xffff0000u); }

// ---------------------------------------------------------------------------
// prep: cast x f32->bf16; bake W images (transpose+bf16+XOR swizzle, exactly
// the gemm LDS layout); zero bcnt.
// ---------------------------------------------------------------------------
#define CAST_BLKS 1600
__global__ __launch_bounds__(256) void prep(
    const float* __restrict__ x, u16* __restrict__ xb, int n8,
    const float* __restrict__ W1r, const float* __restrict__ W1l,
    const float* __restrict__ W2r, const float* __restrict__ W2l,
    const float* __restrict__ W3r, const float* __restrict__ W3l,
    u16* __restrict__ wimg, int* __restrict__ bcnt, int nbuck)
{
    const int bid = blockIdx.x;
    const int tid = threadIdx.x;

    if (bid < CAST_BLKS) {
        int i = bid * 256 + tid;
        if (i < n8) {
            const float4* p = (const float4*)(x + (size_t)i * 8);
            float4 a = p[0], b = p[1];
            uint4 o;
            o.x = f2bf(a.x) | ((u32)f2bf(a.y) << 16);
            o.y = f2bf(a.z) | ((u32)f2bf(a.w) << 16);
            o.z = f2bf(b.x) | ((u32)f2bf(b.y) << 16);
            o.w = f2bf(b.z) | ((u32)f2bf(b.w) << 16);
            *(uint4*)(xb + (size_t)i * 8) = o;
        }
    } else if (bid < CAST_BLKS + 6) {
        int m = bid - CAST_BLKS;            // 0..5
        int layer = m >> 1;                 // 0..2
        int isrel = m & 1;                  // 0 root, 1 rel
        const float* W = (m == 0) ? W1r : (m == 1) ? W1l :
                         (m == 2) ? W2r : (m == 3) ? W2l :
                         (m == 4) ? W3r : W3l;
        u16* img = wimg + (size_t)layer * (64 * 128);
        #pragma unroll
        for (int it = 0; it < 16; ++it) {
            int flat = it * 256 + tid;      // 0..4095
            int k = flat >> 6, n = flat & 63;
            int ck = (k >> 3) + (isrel ? 8 : 0);
            int kin = k & 7;
            img[n * 128 + (((ck ^ (n & 7)) << 3) | kin)] = f2bf(W[k * 64 + n]);
        }
    } else {
        if (tid < nbuck) bcnt[tid] = 0;
    }
}

// ---------------------------------------------------------------------------
// GEMM (MFMA, K=128): hout = bf16(relu([hin | agg] @ [Wroot; Wrel] + b))
// W staged from pre-swizzled image (pure uint4 copy).
// ---------------------------------------------------------------------------
__global__ __launch_bounds__(256) void gemm_cat(
    const u16* __restrict__ hin, const u16* __restrict__ agg,
    const u16* __restrict__ wimg, const float* __restrict__ bias,
    u16* __restrict__ hout, int n_rows)
{
    __shared__ u16 als[64 * 128];   // [row][k0..127], swizzled
    __shared__ u16 wls[64 * 128];   // [col][k0..127], swizzled (from image)

    const int tid = threadIdx.x;
    const int row0 = blockIdx.x * 64;

    // stage W: linear 16KB copy
    {
        const uint4* wsrc = (const uint4*)wimg;
        uint4* wdst = (uint4*)wls;
        #pragma unroll
        for (int it = 0; it < 4; ++it)
            wdst[it * 256 + tid] = wsrc[it * 256 + tid];
    }

    // stage A: 1024 16B chunks; chunk ch<8 from hin, else agg
    #pragma unroll
    for (int it = 0; it < 4; ++it) {
        int id = it * 256 + tid;
        int r = id >> 4, ch = id & 15;
        int gr = row0 + r;
        uint4 v = make_uint4(0, 0, 0, 0);
        if (gr < n_rows) {
            const u16* sp = (ch < 8) ? (hin + (size_t)gr * 64 + ch * 8)
                                     : (agg + (size_t)gr * 64 + (ch - 8) * 8);
            v = *(const uint4*)sp;
        }
        *(uint4*)&als[r * 128 + ((ch ^ (r & 7)) << 3)] = v;
    }
    __syncthreads();

    const int w = tid >> 6, l = tid & 63;
    const int l15 = l & 15;
    const int wrow0 = w * 16;

    short8 afr[4];
    #pragma unroll
    for (int ks = 0; ks < 4; ++ks) {
        int r = wrow0 + l15;
        int ck = ks * 4 + (l >> 4);
        afr[ks] = *(const short8*)&als[r * 128 + ((ck ^ (r & 7)) << 3)];
    }
    short8 bfr[4][4];
    #pragma unroll
    for (int nl = 0; nl < 4; ++nl)
        #pragma unroll
        for (int ks = 0; ks < 4; ++ks) {
            int cl = nl * 16 + l15;
            int ck = ks * 4 + (l >> 4);
            bfr[nl][ks] = *(const short8*)&wls[cl * 128 + ((ck ^ (cl & 7)) << 3)];
        }

    f32x4 acc[4];
    #pragma unroll
    for (int nl = 0; nl < 4; ++nl) {
        float bv = bias[nl * 16 + l15];
        f32x4 iv = {bv, bv, bv, bv};
        acc[nl] = iv;
    }
    #pragma unroll
    for (int nl = 0; nl < 4; ++nl)
        #pragma unroll
        for (int ks = 0; ks < 4; ++ks)
            acc[nl] = __builtin_amdgcn_mfma_f32_16x16x32_bf16(
                afr[ks], bfr[nl][ks], acc[nl], 0, 0, 0);

    // C/D: col = l&15, row = (l>>4)*4 + reg
    const int rg = (l >> 4) * 4;
    #pragma unroll
    for (int reg = 0; reg < 4; ++reg) {
        int row = row0 + wrow0 + rg + reg;
        if (row < n_rows) {
            #pragma unroll
            for (int nl = 0; nl < 4; ++nl)
                hout[(size_t)row * 64 + nl * 16 + l15] =
                    f2bf(fmaxf(acc[nl][reg], 0.f));
        }
    }
}

// ---------------------------------------------------------------------------
// CSR build (R5/R10): partition by dst bucket, then per-bucket local build
// with inline prefix (each block scans bcnt itself; no scan_offsets kernel).
// ---------------------------------------------------------------------------
__global__ __launch_bounds__(256) void part_bucket(
    const int* __restrict__ src, const int* __restrict__ dst, int ne,
    int* __restrict__ bcnt, u32* __restrict__ pairs)
{
    __shared__ int lcnt[256];
    __shared__ int lbase[256];
    const int t = threadIdx.x;
    const int e0 = blockIdx.x * 4096;

    lcnt[t] = 0;
    __syncthreads();

    int s_[16], d_[16];
    #pragma unroll
    for (int i = 0; i < 16; ++i) {
        int e = e0 + i * 256 + t;
        if (e < ne) { s_[i] = src[e]; d_[i] = dst[e]; }
        else        { s_[i] = 0;      d_[i] = -1; }
    }
    #pragma unroll
    for (int i = 0; i < 16; ++i)
        if (d_[i] >= 0) atomicAdd(&lcnt[d_[i] >> 8], 1);
    __syncthreads();

    {
        int c = lcnt[t];
        lbase[t] = (c > 0) ? atomicAdd(&bcnt[t], c) : 0;
    }
    __syncthreads();
    lcnt[t] = 0;
    __syncthreads();

    #pragma unroll
    for (int i = 0; i < 16; ++i)
        if (d_[i] >= 0) {
            int b = d_[i] >> 8;
            int o = atomicAdd(&lcnt[b], 1);
            pairs[(size_t)b * BCAP + lbase[b] + o] =
                (u32)s_[i] | ((u32)(d_[i] & 255) << 16);
        }
}

__global__ __launch_bounds__(256) void build_csr(
    const u32* __restrict__ pairs, const int* __restrict__ bcnt,
    int nn, int nbuck,
    int* __restrict__ row_ptr, u16* __restrict__ csr_src)
{
    __shared__ u32 lp[BCAP];
    __shared__ int deg[256];
    __shared__ int tsum[256];
    __shared__ int lofs[256];
    __shared__ int cur[256];
    __shared__ int s_base[2];    // [0]=ebase, [1]=total

    const int b = blockIdx.x;
    const int t = threadIdx.x;
    const int cnt = bcnt[b];
    const int n0  = b * 256;

    // inline exclusive prefix over bcnt (replaces scan_offsets kernel)
    if (t < 64) {
        int pre = 0, tot = 0;
        for (int i = t; i < nbuck; i += 64) {
            int v = bcnt[i];
            tot += v;
            if (i < b) pre += v;
        }
        #pragma unroll
        for (int msk = 1; msk < 64; msk <<= 1) {
            pre += __shfl_xor(pre, msk);
            tot += __shfl_xor(tot, msk);
        }
        if (t == 0) { s_base[0] = pre; s_base[1] = tot; }
    }
    deg[t] = 0; cur[t] = 0;
    __syncthreads();

    const int ebase = s_base[0];
    if (b == nbuck - 1 && t == 0) row_ptr[nn] = s_base[1];

    for (int i = t; i < cnt; i += 256) {
        u32 p = pairs[(size_t)b * BCAP + i];
        lp[i] = p;
        atomicAdd(&deg[p >> 16], 1);
    }
    __syncthreads();

    tsum[t] = deg[t];
    __syncthreads();
    #pragma unroll
    for (int off = 1; off < 256; off <<= 1) {
        int x = (t >= off) ? tsum[t - off] : 0;
        __syncthreads();
        tsum[t] += x;
        __syncthreads();
    }
    int excl = (t > 0 ? tsum[t - 1] : 0);
    lofs[t] = ebase + excl;
    int node = n0 + t;
    if (node < nn) row_ptr[node] = ebase + excl;
    __syncthreads();

    for (int i = t; i < cnt; i += 256) {
        u32 p = lp[i];
        int dl = p >> 16;
        int pos = lofs[dl] + atomicAdd(&cur[dl], 1);
        csr_src[pos] = (u16)(p & 0xffffu);
    }
}

// ---------------------------------------------------------------------------
// Gather-aggregate (R6 + 2-deep ILP): agg[node] = bf16(sum h_bf[src_j])
// One wave/node. Lane (slot=l>>3, chunk=l&7); 2 independent uint4 loads per
// iteration (j+=16); shfl_xor(8/16/32) slot reduce; slot-0 writes 128B row.
// ---------------------------------------------------------------------------
__global__ __launch_bounds__(256) void gather_agg(
    const u16* __restrict__ hb,
    const int* __restrict__ row_ptr,
    const u16* __restrict__ csr_src,
    u16* __restrict__ agg,
    int nn)
{
    const int node = blockIdx.x * 4 + (threadIdx.x >> 6);
    const int l = threadIdx.x & 63;
    if (node >= nn) return;
    const int s = row_ptr[node];
    const int e = row_ptr[node + 1];
    const int es = l >> 3;      // edge slot 0..7
    const int c  = l & 7;       // 16B chunk 0..7
    const uint4* hv = (const uint4*)hb;   // row = 8 uint4

    float a0=0.f,a1=0.f,a2=0.f,a3=0.f,a4=0.f,a5=0.f,a6=0.f,a7=0.f;
    for (int j = s; j < e; j += 16) {
        int je0 = j + es, je1 = j + es + 8;
        int jj0 = (je0 < e) ? je0 : (e - 1);
        int jj1 = (je1 < e) ? je1 : (e - 1);
        float m0 = (je0 < e) ? 1.f : 0.f;
        float m1 = (je1 < e) ? 1.f : 0.f;
        int s0 = csr_src[jj0];
        int s1 = csr_src[jj1];
        uint4 q0 = hv[(size_t)s0 * 8 + c];
        uint4 q1 = hv[(size_t)s1 * 8 + c];
        a0 = fmaf(m0, bflo(q0.x), a0);  a1 = fmaf(m0, bfhi(q0.x), a1);
        a2 = fmaf(m0, bflo(q0.y), a2);  a3 = fmaf(m0, bfhi(q0.y), a3);
        a4 = fmaf(m0, bflo(q0.z), a4);  a5 = fmaf(m0, bfhi(q0.z), a5);
        a6 = fmaf(m0, bflo(q0.w), a6);  a7 = fmaf(m0, bfhi(q0.w), a7);
        a0 = fmaf(m1, bflo(q1.x), a0);  a1 = fmaf(m1, bfhi(q1.x), a1);
        a2 = fmaf(m1, bflo(q1.y), a2);  a3 = fmaf(m1, bfhi(q1.y), a3);
        a4 = fmaf(m1, bflo(q1.z), a4);  a5 = fmaf(m1, bfhi(q1.z), a5);
        a6 = fmaf(m1, bflo(q1.w), a6);  a7 = fmaf(m1, bfhi(q1.w), a7);
    }
    #pragma unroll
    for (int msk = 8; msk <= 32; msk <<= 1) {
        a0 += __shfl_xor(a0, msk); a1 += __shfl_xor(a1, msk);
        a2 += __shfl_xor(a2, msk); a3 += __shfl_xor(a3, msk);
        a4 += __shfl_xor(a4, msk); a5 += __shfl_xor(a5, msk);
        a6 += __shfl_xor(a6, msk); a7 += __shfl_xor(a7, msk);
    }
    if (es == 0) {
        uint4 o;
        o.x = f2bf(a0) | ((u32)f2bf(a1) << 16);
        o.y = f2bf(a2) | ((u32)f2bf(a3) << 16);
        o.z = f2bf(a4) | ((u32)f2bf(a5) << 16);
        o.w = f2bf(a6) | ((u32)f2bf(a7) << 16);
        ((uint4*)agg)[(size_t)node * 8 + c] = o;
    }
}

// ---------------------------------------------------------------------------
// Pool (mean over sorted batch segments; h is bf16, relu pre-applied) + MLP.
// ---------------------------------------------------------------------------
__global__ __launch_bounds__(256) void pool_mlp(
    const u16* __restrict__ h,
    const int* __restrict__ batch,
    int n_nodes,
    const float* __restrict__ Wf1, const float* __restrict__ bf1,
    const float* __restrict__ Wf2, const float* __restrict__ bf2,
    float* __restrict__ out, int n_graphs)
{
    const int g = blockIdx.x;
    const int tid = threadIdx.x;

    int lo = 0, hi = n_nodes;
    while (lo < hi) { int mid = (lo + hi) >> 1; if (batch[mid] < g) lo = mid + 1; else hi = mid; }
    int s = lo;
    lo = s; hi = n_nodes;
    while (lo < hi) { int mid = (lo + hi) >> 1; if (batch[mid] < g + 1) lo = mid + 1; else hi = mid; }
    int e = lo;

    const int c16 = tid & 15;        // feature quad (c16*4 .. c16*4+3)
    const int r16 = tid >> 4;        // row group 0..15
    const uint2* hv = (const uint2*)h;   // row = 16 uint2

    float4 acc = make_float4(0.f, 0.f, 0.f, 0.f);
    for (int i = s + r16; i < e; i += 16) {
        uint2 q = hv[(size_t)i * 16 + c16];
        acc.x += bflo(q.x); acc.y += bfhi(q.x);
        acc.z += bflo(q.y); acc.w += bfhi(q.y);
    }

    __shared__ float4 red[256];
    red[tid] = acc;
    __syncthreads();
    #pragma unroll
    for (int off = 8; off > 0; off >>= 1) {
        if (r16 < off) {
            float4 o = red[tid + off * 16];
            float4 m = red[tid];
            m.x += o.x; m.y += o.y; m.z += o.z; m.w += o.w;
            red[tid] = m;
        }
        __syncthreads();
    }

    __shared__ float pl[64];
    __shared__ float md[64];
    if (r16 == 0) {
        float inv = 1.0f / (float)((e - s) > 0 ? (e - s) : 1);
        float4 m = red[c16];
        pl[c16 * 4 + 0] = m.x * inv;
        pl[c16 * 4 + 1] = m.y * inv;
        pl[c16 * 4 + 2] = m.z * inv;
        pl[c16 * 4 + 3] = m.w * inv;
    }
    __syncthreads();

    if (tid < 64) {
        float m = bf1[tid];
        #pragma unroll 8
        for (int k = 0; k < 64; ++k)
            m += pl[k] * Wf1[k * 64 + tid];
        md[tid] = m;
    }
    __syncthreads();

    if (tid < 2) {
        float o = bf2[tid];
        #pragma unroll 8
        for (int k = 0; k < 64; ++k)
            o += md[k] * Wf2[k * 2 + tid];
        out[(size_t)g * 2 + tid] = o;
    }
}

// ---------------------------------------------------------------------------
extern "C" void kernel_launch(void* const* d_in, const int* in_sizes, int n_in,
                              void* d_out, int out_size, void* d_ws, size_t ws_size,
                              hipStream_t stream) {
    const float* x     = (const float*)d_in[0];
    const int*   ei    = (const int*)d_in[1];
    const int*   batch = (const int*)d_in[2];
    const float* W1_rel  = (const float*)d_in[3];
    const float* W1_root = (const float*)d_in[4];
    const float* b1      = (const float*)d_in[5];
    const float* W2_rel  = (const float*)d_in[6];
    const float* W2_root = (const float*)d_in[7];
    const float* b2      = (const float*)d_in[8];
    const float* W3_rel  = (const float*)d_in[9];
    const float* W3_root = (const float*)d_in[10];
    const float* b3      = (const float*)d_in[11];
    const float* Wf1     = (const float*)d_in[12];
    const float* bf1     = (const float*)d_in[13];
    const float* Wf2     = (const float*)d_in[14];
    const float* bf2     = (const float*)d_in[15];

    const int NN = in_sizes[0] / NFEAT;      // 50000
    const int NE = in_sizes[1] / 2;          // 800000
    const int NG = out_size / 2;             // 500

    const int* src = ei;
    const int* dst = ei + NE;

    const int nbuck = (NN + 255) / 256;      // 196

    u16*   hA      = (u16*)d_ws;                             // NN*64 bf16
    u16*   hB      = hA + (size_t)NN * NFEAT;                // NN*64 bf16 (also x_bf)
    u16*   aggb    = hB + (size_t)NN * NFEAT;                // NN*64 bf16
    int*   row_ptr = (int*)(aggb + (size_t)NN * NFEAT);      // NN+1
    int*   bcnt    = row_ptr + (NN + 1);                     // nbuck
    u32*   pairs   = (u32*)(bcnt + nbuck);                   // nbuck*BCAP
    u16*   csr_src = (u16*)(pairs + (size_t)nbuck * BCAP);   // NE u16
    u16*   wimg    = csr_src + NE;                           // 3*64*128 u16

    const int gemm_grid = (NN + 63) / 64;
    const int node_grid = (NN + 3) / 4;
    const int part_grid = (NE + 4095) / 4096;                // 196
    const int n8        = NN * NFEAT / 8;                    // 400000

    // ---- prep: x->bf16 (hB), W images, zero bcnt ----
    prep<<<CAST_BLKS + 7, 256, 0, stream>>>(x, hB, n8,
        W1_root, W1_rel, W2_root, W2_rel, W3_root, W3_rel, wimg, bcnt, nbuck);

    // ---- CSR build (reused by all 3 layers) ----
    part_bucket<<<part_grid, 256, 0, stream>>>(src, dst, NE, bcnt, pairs);
    build_csr<<<nbuck, 256, 0, stream>>>(pairs, bcnt, NN, nbuck, row_ptr, csr_src);

    // Layer 1: x_bf (=hB) -> hA
    gather_agg<<<node_grid, 256, 0, stream>>>(hB, row_ptr, csr_src, aggb, NN);
    gemm_cat<<<gemm_grid, 256, 0, stream>>>(hB, aggb, wimg, b1, hA, NN);

    // Layer 2: hA -> hB
    gather_agg<<<node_grid, 256, 0, stream>>>(hA, row_ptr, csr_src, aggb, NN);
    gemm_cat<<<gemm_grid, 256, 0, stream>>>(hA, aggb, wimg + 64 * 128, b2, hB, NN);

    // Layer 3: hB -> hA
    gather_agg<<<node_grid, 256, 0, stream>>>(hB, row_ptr, csr_src, aggb, NN);
    gemm_cat<<<gemm_grid, 256, 0, stream>>>(hB, aggb, wimg + 2 * 64 * 128, b3, hA, NN);

    // Pool + MLP head
    pool_mlp<<<NG, 256, 0, stream>>>(hA, batch, NN, Wf1, bf1, Wf2, bf2, (float*)d_out, NG);
}